// Round 1
// baseline (250.949 us; speedup 1.0000x reference)
//
#include <hip/hip_runtime.h>
#include <math.h>

#define N_DIM 4096
#define H_DIM 256
#define C_DIM 151
#define KP    416   // 256 + 151 padded to multiple of 16

// ---------------- workspace layout (float offsets) ----------------
// 0        : ls[256]          (label_scores, padded)
// 256      : s[4096]
// 4352     : sub[N*H]
// 1052928  : obj[N*H]
// 2101504  : Apack[N*KP]      (obj*w_mul | w_ps*D)
// 3805440  : Bpack[N*KP]      (sub       | M = D@C)
// 5509376  : rowbias[4096]
// 5513472  : colbias[4096]
#define WS_LS      0
#define WS_S       256
#define WS_SUB     4352
#define WS_OBJ     1052928
#define WS_APACK   2101504
#define WS_BPACK   3805440
#define WS_ROWB    5509376
#define WS_COLB    5513472

// label_scores[c] = sum_b co[c,b]
__global__ void k_label(const float* __restrict__ co, float* __restrict__ ls) {
    int t = threadIdx.x;
    if (t < C_DIM) {
        float a = 0.f;
        for (int b = 0; b < C_DIM; ++b) a += co[t * C_DIM + b];
        ls[t] = a;
    }
}

// s[i] = sum_c D[i,c] * ls[c]
__global__ void k_s(const float* __restrict__ D, const float* __restrict__ ls,
                    float* __restrict__ s) {
    int i = blockIdx.x * blockDim.x + threadIdx.x;
    float a = 0.f;
    for (int c = 0; c < C_DIM; ++c) a += D[i * C_DIM + c] * ls[c];
    s[i] = a;
}

// sub = relu(P @ W_sub + b_sub); obj = relu(P @ W_obj + b_obj)
// 64x64 tile, 16x16 threads, 4x4 per thread, K=256
__global__ __launch_bounds__(256) void k_subobj(
    const float* __restrict__ P,
    const float* __restrict__ Wsub, const float* __restrict__ bsub,
    const float* __restrict__ Wobj, const float* __restrict__ bobj,
    float* __restrict__ sub, float* __restrict__ obj) {
    const int z = blockIdx.z;
    const float* W    = z ? Wobj : Wsub;
    const float* bias = z ? bobj : bsub;
    float* out        = z ? obj  : sub;

    const int h0 = blockIdx.x * 64;
    const int i0 = blockIdx.y * 64;
    const int tx = threadIdx.x, ty = threadIdx.y;
    const int t  = ty * 16 + tx;

    __shared__ float Ps[16][68];  // [k][m]
    __shared__ float Ws[16][68];  // [k][h]

    float acc[4][4] = {};

    for (int k0 = 0; k0 < H_DIM; k0 += 16) {
        // load P tile (64 rows x 16 k), transposed into Ps[k][m]
        {
            int row = t >> 2;
            int kq  = (t & 3) * 4;
            float4 f = *(const float4*)&P[(size_t)(i0 + row) * H_DIM + k0 + kq];
            Ps[kq + 0][row] = f.x; Ps[kq + 1][row] = f.y;
            Ps[kq + 2][row] = f.z; Ps[kq + 3][row] = f.w;
        }
        // load W tile (16 k x 64 h) natural into Ws[k][h]
        {
            int k  = t >> 4;
            int h4 = (t & 15) * 4;
            float4 f = *(const float4*)&W[(size_t)(k0 + k) * H_DIM + h0 + h4];
            Ws[k][h4 + 0] = f.x; Ws[k][h4 + 1] = f.y;
            Ws[k][h4 + 2] = f.z; Ws[k][h4 + 3] = f.w;
        }
        __syncthreads();
        #pragma unroll
        for (int kk = 0; kk < 16; ++kk) {
            float a[4], b[4];
            #pragma unroll
            for (int u = 0; u < 4; ++u) a[u] = Ps[kk][ty * 4 + u];
            #pragma unroll
            for (int u = 0; u < 4; ++u) b[u] = Ws[kk][tx * 4 + u];
            #pragma unroll
            for (int m = 0; m < 4; ++m)
                #pragma unroll
                for (int n = 0; n < 4; ++n)
                    acc[m][n] += a[m] * b[n];
        }
        __syncthreads();
    }

    #pragma unroll
    for (int m = 0; m < 4; ++m) {
        int i = i0 + ty * 4 + m;
        #pragma unroll
        for (int n = 0; n < 4; ++n) {
            int h = h0 + tx * 4 + n;
            float v = acc[m][n] + bias[h];
            out[(size_t)i * H_DIM + h] = v > 0.f ? v : 0.f;
        }
    }
}

// Pack A = [obj*w_mul | w_ps*D], B = [sub | M=D@C], zero K-padding.
// grid (N, 2), 256 threads
__global__ void k_pack(const float* __restrict__ sub, const float* __restrict__ obj,
                       const float* __restrict__ D, const float* __restrict__ co,
                       const float* __restrict__ wsc,
                       float* __restrict__ Apack, float* __restrict__ Bpack) {
    __shared__ float Drow[C_DIM];
    const int i = blockIdx.x;
    const int t = threadIdx.x;
    if (blockIdx.y == 0) {
        // kp in [0,256): main GEMM operands
        Apack[(size_t)i * KP + t] = obj[(size_t)i * H_DIM + t] * wsc[t];
        Bpack[(size_t)i * KP + t] = sub[(size_t)i * H_DIM + t];
    } else {
        if (t < C_DIM) Drow[t] = D[(size_t)i * C_DIM + t];
        __syncthreads();
        if (t < KP - H_DIM) {  // t < 160
            int kp = H_DIM + t;
            float av = 0.f, bv = 0.f;
            if (t < C_DIM) {
                av = wsc[768] * Drow[t];   // w_ps * D[i,b]
                float m = 0.f;
                for (int a = 0; a < C_DIM; ++a)
                    m += Drow[a] * co[a * C_DIM + t];  // M[i,t]
                bv = m;
            }
            Apack[(size_t)i * KP + kp] = av;
            Bpack[(size_t)i * KP + kp] = bv;
        }
    }
}

// rowbias[i] = obj[i].w_o + w_os*s[i] ; colbias[j] = sub[j].w_s + w_ss*s[j] + b
__global__ void k_bias(const float* __restrict__ sub, const float* __restrict__ obj,
                       const float* __restrict__ s, const float* __restrict__ wsc,
                       const float* __restrict__ bsc,
                       float* __restrict__ rowbias, float* __restrict__ colbias) {
    int i = blockIdx.x * blockDim.x + threadIdx.x;
    float ro = 0.f, cb = 0.f;
    for (int h = 0; h < H_DIM; ++h) {
        ro += obj[(size_t)i * H_DIM + h] * wsc[512 + h];
        cb += sub[(size_t)i * H_DIM + h] * wsc[256 + h];
    }
    rowbias[i] = ro + wsc[770] * s[i];
    colbias[i] = cb + wsc[769] * s[i] + bsc[0];
}

// out[i*N+j] = sigmoid( sum_k Apack[i,k]*Bpack[j,k] + rowbias[i] + colbias[j] )
// 128x128 tile, 256 threads, 8x8 per thread, BK=16
__global__ __launch_bounds__(256) void k_main(
    const float* __restrict__ Apack, const float* __restrict__ Bpack,
    const float* __restrict__ rowbias, const float* __restrict__ colbias,
    float* __restrict__ out) {
    __shared__ float As[16][132];  // [k][m]
    __shared__ float Bs[16][132];  // [k][n]

    const int t  = threadIdx.x;
    const int tx = t & 15, ty = t >> 4;
    const int i0 = blockIdx.y * 128;
    const int j0 = blockIdx.x * 128;

    float acc[8][8] = {};

    for (int k0 = 0; k0 < KP; k0 += 16) {
        #pragma unroll
        for (int r = 0; r < 2; ++r) {
            int idx = t + r * 256;           // 0..511
            int row = idx >> 2;              // 0..127
            int kq  = (idx & 3) * 4;         // 0,4,8,12
            float4 fa = *(const float4*)&Apack[(size_t)(i0 + row) * KP + k0 + kq];
            float4 fb = *(const float4*)&Bpack[(size_t)(j0 + row) * KP + k0 + kq];
            As[kq + 0][row] = fa.x; As[kq + 1][row] = fa.y;
            As[kq + 2][row] = fa.z; As[kq + 3][row] = fa.w;
            Bs[kq + 0][row] = fb.x; Bs[kq + 1][row] = fb.y;
            Bs[kq + 2][row] = fb.z; Bs[kq + 3][row] = fb.w;
        }
        __syncthreads();
        #pragma unroll
        for (int kk = 0; kk < 16; ++kk) {
            float a[8], b[8];
            #pragma unroll
            for (int u = 0; u < 8; ++u) a[u] = As[kk][ty * 8 + u];
            #pragma unroll
            for (int u = 0; u < 8; ++u) b[u] = Bs[kk][tx * 8 + u];
            #pragma unroll
            for (int m = 0; m < 8; ++m)
                #pragma unroll
                for (int n = 0; n < 8; ++n)
                    acc[m][n] += a[m] * b[n];
        }
        __syncthreads();
    }

    #pragma unroll
    for (int m = 0; m < 8; ++m) {
        int i = i0 + ty * 8 + m;
        float rb = rowbias[i];
        #pragma unroll
        for (int n = 0; n < 8; ++n) {
            int j = j0 + tx * 8 + n;
            float v = acc[m][n] + rb + colbias[j];
            out[(size_t)i * N_DIM + j] = 1.0f / (1.0f + __expf(-v));
        }
    }
}

extern "C" void kernel_launch(void* const* d_in, const int* in_sizes, int n_in,
                              void* d_out, int out_size, void* d_ws, size_t ws_size,
                              hipStream_t stream) {
    const float* prepro = (const float*)d_in[0];
    const float* D      = (const float*)d_in[1];
    const float* co     = (const float*)d_in[2];
    const float* Wsub   = (const float*)d_in[3];
    const float* bsub   = (const float*)d_in[4];
    const float* Wobj   = (const float*)d_in[5];
    const float* bobj   = (const float*)d_in[6];
    const float* wsc    = (const float*)d_in[7];
    const float* bsc    = (const float*)d_in[8];
    float* out = (float*)d_out;

    float* ws      = (float*)d_ws;
    float* ls      = ws + WS_LS;
    float* s       = ws + WS_S;
    float* sub     = ws + WS_SUB;
    float* obj     = ws + WS_OBJ;
    float* Apack   = ws + WS_APACK;
    float* Bpack   = ws + WS_BPACK;
    float* rowbias = ws + WS_ROWB;
    float* colbias = ws + WS_COLB;

    k_label<<<1, 256, 0, stream>>>(co, ls);
    k_s<<<N_DIM / 256, 256, 0, stream>>>(D, ls, s);
    k_subobj<<<dim3(H_DIM / 64, N_DIM / 64, 2), dim3(16, 16), 0, stream>>>(
        prepro, Wsub, bsub, Wobj, bobj, sub, obj);
    k_pack<<<dim3(N_DIM, 2), 256, 0, stream>>>(sub, obj, D, co, wsc, Apack, Bpack);
    k_bias<<<N_DIM / 256, 256, 0, stream>>>(sub, obj, s, wsc, bsc, rowbias, colbias);
    k_main<<<dim3(N_DIM / 128, N_DIM / 128), 256, 0, stream>>>(
        Apack, Bpack, rowbias, colbias, out);
}

// Round 2
// 132.441 us; speedup vs baseline: 1.8948x; 1.8948x over previous
//
#include <hip/hip_runtime.h>
#include <hip/hip_bf16.h>
#include <math.h>

#define N_DIM 4096
#define H_DIM 256
#define C_DIM 151
#define KP    416   // 256 + 151 padded to multiple of 32 (13 K-steps of 32)

typedef unsigned short ushort_t;
typedef __attribute__((ext_vector_type(8))) short bf16x8;
typedef __attribute__((ext_vector_type(4))) float f32x4;

// ---------------- workspace layout (BYTE offsets) ----------------
#define WSB_LS     0          // f32[256]
#define WSB_S      1024       // f32[4096]
#define WSB_SUB    17408      // f32[N*H]
#define WSB_OBJ    4211712    // f32[N*H]
#define WSB_ROWB   8406016    // f32[4096]
#define WSB_COLB   8422400    // f32[4096]
#define WSB_APACK  8438784    // bf16[N*KP]  (obj*w_mul | w_ps*D)
#define WSB_BPACK  11847680   // bf16[N*KP]  (sub       | M = D@C)

// label_scores[c] = sum_b co[c,b]
__global__ void k_label(const float* __restrict__ co, float* __restrict__ ls) {
    int t = threadIdx.x;
    if (t < C_DIM) {
        float a = 0.f;
        for (int b = 0; b < C_DIM; ++b) a += co[t * C_DIM + b];
        ls[t] = a;
    }
}

// s[i] = sum_c D[i,c] * ls[c]
__global__ void k_s(const float* __restrict__ D, const float* __restrict__ ls,
                    float* __restrict__ s) {
    int i = blockIdx.x * blockDim.x + threadIdx.x;
    float a = 0.f;
    for (int c = 0; c < C_DIM; ++c) a += D[i * C_DIM + c] * ls[c];
    s[i] = a;
}

// sub = relu(P @ W_sub + b_sub); obj = relu(P @ W_obj + b_obj)
// Fused epilogue: Bpack[:, :256] = bf16(sub); Apack[:, :256] = bf16(obj * w_mul)
__global__ __launch_bounds__(256) void k_subobj(
    const float* __restrict__ P,
    const float* __restrict__ Wsub, const float* __restrict__ bsub,
    const float* __restrict__ Wobj, const float* __restrict__ bobj,
    const float* __restrict__ wsc,
    float* __restrict__ sub, float* __restrict__ obj,
    __hip_bfloat16* __restrict__ Apack, __hip_bfloat16* __restrict__ Bpack) {
    const int z = blockIdx.z;
    const float* W    = z ? Wobj : Wsub;
    const float* bias = z ? bobj : bsub;
    float* out        = z ? obj  : sub;

    const int h0 = blockIdx.x * 64;
    const int i0 = blockIdx.y * 64;
    const int tx = threadIdx.x, ty = threadIdx.y;
    const int t  = ty * 16 + tx;

    __shared__ float Ps[16][68];
    __shared__ float Ws[16][68];

    float acc[4][4] = {};

    for (int k0 = 0; k0 < H_DIM; k0 += 16) {
        {
            int row = t >> 2;
            int kq  = (t & 3) * 4;
            float4 f = *(const float4*)&P[(size_t)(i0 + row) * H_DIM + k0 + kq];
            Ps[kq + 0][row] = f.x; Ps[kq + 1][row] = f.y;
            Ps[kq + 2][row] = f.z; Ps[kq + 3][row] = f.w;
        }
        {
            int k  = t >> 4;
            int h4 = (t & 15) * 4;
            float4 f = *(const float4*)&W[(size_t)(k0 + k) * H_DIM + h0 + h4];
            Ws[k][h4 + 0] = f.x; Ws[k][h4 + 1] = f.y;
            Ws[k][h4 + 2] = f.z; Ws[k][h4 + 3] = f.w;
        }
        __syncthreads();
        #pragma unroll
        for (int kk = 0; kk < 16; ++kk) {
            float a[4], b[4];
            #pragma unroll
            for (int u = 0; u < 4; ++u) a[u] = Ps[kk][ty * 4 + u];
            #pragma unroll
            for (int u = 0; u < 4; ++u) b[u] = Ws[kk][tx * 4 + u];
            #pragma unroll
            for (int m = 0; m < 4; ++m)
                #pragma unroll
                for (int n = 0; n < 4; ++n)
                    acc[m][n] += a[m] * b[n];
        }
        __syncthreads();
    }

    #pragma unroll
    for (int m = 0; m < 4; ++m) {
        int i = i0 + ty * 4 + m;
        #pragma unroll
        for (int n = 0; n < 4; ++n) {
            int h = h0 + tx * 4 + n;
            float v = acc[m][n] + bias[h];
            v = v > 0.f ? v : 0.f;
            out[(size_t)i * H_DIM + h] = v;
            if (z) Apack[(size_t)i * KP + h] = __float2bfloat16(v * wsc[h]);
            else   Bpack[(size_t)i * KP + h] = __float2bfloat16(v);
        }
    }
}

// Tail pack: Apack[i, 256+t] = w_ps * D[i,t]; Bpack[i, 256+t] = (D @ co)[i,t]
// zero for t in [151,160). grid = N, 192 threads.
__global__ __launch_bounds__(192) void k_pack_tail(
    const float* __restrict__ D, const float* __restrict__ co,
    const float* __restrict__ wsc,
    __hip_bfloat16* __restrict__ Apack, __hip_bfloat16* __restrict__ Bpack) {
    __shared__ float Drow[C_DIM];
    const int i = blockIdx.x;
    const int t = threadIdx.x;
    if (t < C_DIM) Drow[t] = D[(size_t)i * C_DIM + t];
    __syncthreads();
    if (t < KP - H_DIM) {  // t < 160
        float av = 0.f, bv = 0.f;
        if (t < C_DIM) {
            av = wsc[768] * Drow[t];
            float m = 0.f;
            for (int a = 0; a < C_DIM; ++a)
                m += Drow[a] * co[a * C_DIM + t];
            bv = m;
        }
        Apack[(size_t)i * KP + H_DIM + t] = __float2bfloat16(av);
        Bpack[(size_t)i * KP + H_DIM + t] = __float2bfloat16(bv);
    }
}

// rowbias[i] = obj[i].w_o + w_os*s[i] ; colbias[j] = sub[j].w_s + w_ss*s[j] + b
__global__ void k_bias(const float* __restrict__ sub, const float* __restrict__ obj,
                       const float* __restrict__ s, const float* __restrict__ wsc,
                       const float* __restrict__ bsc,
                       float* __restrict__ rowbias, float* __restrict__ colbias) {
    int i = blockIdx.x * blockDim.x + threadIdx.x;
    float ro = 0.f, cb = 0.f;
    for (int h = 0; h < H_DIM; ++h) {
        ro += obj[(size_t)i * H_DIM + h] * wsc[512 + h];
        cb += sub[(size_t)i * H_DIM + h] * wsc[256 + h];
    }
    rowbias[i] = ro + wsc[770] * s[i];
    colbias[i] = cb + wsc[769] * s[i] + bsc[0];
}

// MFMA main: out[i,j] = sigmoid( A[i,:].B[j,:] + rowbias[i] + colbias[j] )
// 128x128 tile, 4 waves (2x2), each wave 64x64, BK=32, 16x16x32 bf16 MFMA.
// LDS staged via global_load_lds(16B) with chunk-XOR swizzle:
//   LDS linear chunk idx holds global chunk ((idx&3)^(row&3)) of row idx>>2.
__global__ __launch_bounds__(256) void k_main(
    const ushort_t* __restrict__ Apack, const ushort_t* __restrict__ Bpack,
    const float* __restrict__ rowbias, const float* __restrict__ colbias,
    float* __restrict__ out) {
    __shared__ ushort_t As[128 * 32];
    __shared__ ushort_t Bs[128 * 32];

    const int t  = threadIdx.x;
    const int w  = t >> 6, l = t & 63;
    const int wr = w >> 1, wc = w & 1;
    const int lr = l & 15;       // A row / B col within 16-frag
    const int g  = l >> 4;       // k-chunk 0..3 (8 bf16 each)
    const int i0 = blockIdx.y * 128;
    const int j0 = blockIdx.x * 128;

    f32x4 acc[4][4] = {{{0.f,0.f,0.f,0.f}}};
    #pragma unroll
    for (int m = 0; m < 4; ++m)
        #pragma unroll
        for (int n = 0; n < 4; ++n)
            acc[m][n] = f32x4{0.f, 0.f, 0.f, 0.f};

    for (int ks = 0; ks < KP / 32; ++ks) {
        const int k0 = ks * 32;
        #pragma unroll
        for (int r = 0; r < 2; ++r) {
            int idx = t + r * 256;              // 0..511 = 16B chunk index
            int row = idx >> 2;                 // 0..127
            int sc  = (idx & 3) ^ (row & 3);    // pre-swizzled source chunk
            const ushort_t* ga = Apack + (size_t)(i0 + row) * KP + k0 + sc * 8;
            const ushort_t* gb = Bpack + (size_t)(j0 + row) * KP + k0 + sc * 8;
            __builtin_amdgcn_global_load_lds(
                (const __attribute__((address_space(1))) void*)ga,
                (__attribute__((address_space(3))) void*)(As + idx * 8), 16, 0, 0);
            __builtin_amdgcn_global_load_lds(
                (const __attribute__((address_space(1))) void*)gb,
                (__attribute__((address_space(3))) void*)(Bs + idx * 8), 16, 0, 0);
        }
        __syncthreads();

        bf16x8 a[4], b[4];
        #pragma unroll
        for (int m = 0; m < 4; ++m) {
            int Rl = wr * 64 + m * 16 + lr;
            int ch = (Rl << 2) | (g ^ (Rl & 3));   // swizzled read chunk
            a[m] = *(const bf16x8*)(As + ch * 8);
        }
        #pragma unroll
        for (int n = 0; n < 4; ++n) {
            int Rl = wc * 64 + n * 16 + lr;
            int ch = (Rl << 2) | (g ^ (Rl & 3));
            b[n] = *(const bf16x8*)(Bs + ch * 8);
        }
        #pragma unroll
        for (int m = 0; m < 4; ++m)
            #pragma unroll
            for (int n = 0; n < 4; ++n)
                acc[m][n] = __builtin_amdgcn_mfma_f32_16x16x32_bf16(
                    a[m], b[n], acc[m][n], 0, 0, 0);
        __syncthreads();
    }

    // epilogue: C/D layout col = lane&15, row = (lane>>4)*4 + reg
    const int rbase = g * 4;
    #pragma unroll
    for (int m = 0; m < 4; ++m) {
        float rb[4];
        #pragma unroll
        for (int r = 0; r < 4; ++r)
            rb[r] = rowbias[i0 + wr * 64 + m * 16 + rbase + r];
        #pragma unroll
        for (int n = 0; n < 4; ++n) {
            int j = j0 + wc * 64 + n * 16 + lr;
            float cb = colbias[j];
            #pragma unroll
            for (int r = 0; r < 4; ++r) {
                int i = i0 + wr * 64 + m * 16 + rbase + r;
                float v = acc[m][n][r] + rb[r] + cb;
                out[(size_t)i * N_DIM + j] = 1.0f / (1.0f + __expf(-v));
            }
        }
    }
}

extern "C" void kernel_launch(void* const* d_in, const int* in_sizes, int n_in,
                              void* d_out, int out_size, void* d_ws, size_t ws_size,
                              hipStream_t stream) {
    const float* prepro = (const float*)d_in[0];
    const float* D      = (const float*)d_in[1];
    const float* co     = (const float*)d_in[2];
    const float* Wsub   = (const float*)d_in[3];
    const float* bsub   = (const float*)d_in[4];
    const float* Wobj   = (const float*)d_in[5];
    const float* bobj   = (const float*)d_in[6];
    const float* wsc    = (const float*)d_in[7];
    const float* bsc    = (const float*)d_in[8];
    float* out = (float*)d_out;

    char* ws = (char*)d_ws;
    float* ls      = (float*)(ws + WSB_LS);
    float* s       = (float*)(ws + WSB_S);
    float* sub     = (float*)(ws + WSB_SUB);
    float* obj     = (float*)(ws + WSB_OBJ);
    float* rowbias = (float*)(ws + WSB_ROWB);
    float* colbias = (float*)(ws + WSB_COLB);
    __hip_bfloat16* Apack = (__hip_bfloat16*)(ws + WSB_APACK);
    __hip_bfloat16* Bpack = (__hip_bfloat16*)(ws + WSB_BPACK);

    k_label<<<1, 256, 0, stream>>>(co, ls);
    k_s<<<N_DIM / 256, 256, 0, stream>>>(D, ls, s);
    k_subobj<<<dim3(H_DIM / 64, N_DIM / 64, 2), dim3(16, 16), 0, stream>>>(
        prepro, Wsub, bsub, Wobj, bobj, wsc, sub, obj, Apack, Bpack);
    k_pack_tail<<<N_DIM, 192, 0, stream>>>(D, co, wsc, Apack, Bpack);
    k_bias<<<N_DIM / 256, 256, 0, stream>>>(sub, obj, s, wsc, bsc, rowbias, colbias);
    k_main<<<dim3(N_DIM / 128, N_DIM / 128), 256, 0, stream>>>(
        (const ushort_t*)Apack, (const ushort_t*)Bpack, rowbias, colbias, out);
}

// Round 3
// 101.235 us; speedup vs baseline: 2.4789x; 1.3083x over previous
//
#include <hip/hip_runtime.h>
#include <hip/hip_bf16.h>
#include <math.h>

#define N_DIM 4096
#define H_DIM 256
#define C_DIM 151
#define KP    416   // 256 + 160 (151 padded); 13 K-steps of 32

typedef unsigned short ushort_t;
typedef __attribute__((ext_vector_type(8))) short bf16x8;
typedef __attribute__((ext_vector_type(4))) float f32x4;

// ---------------- workspace layout (BYTE offsets) ----------------
#define WSB_LS     0          // f32[256]
#define WSB_S      1024       // f32[4096]
#define WSB_PPACK  17408      // bf16[4096*256]  (P rounded)
#define WSB_WT     2114560    // bf16[2][256*256] (W_sub^T | W_obj^T, k-contiguous)
#define WSB_PART   2376704    // f32[16][4096] bias partials
#define WSB_ROWB   2638848    // f32[4096]
#define WSB_COLB   2655232    // f32[4096]
#define WSB_APACK  2671616    // bf16[4096*416]  (obj*w_mul | w_ps*D)
#define WSB_BPACK  6079488    // bf16[4096*416]  (sub       | D@co)

// label_scores[c] = sum_b co[c,b]
__global__ void k_label(const float* __restrict__ co, float* __restrict__ ls) {
    int t = threadIdx.x;
    if (t < C_DIM) {
        float a = 0.f;
        for (int b = 0; b < C_DIM; ++b) a += co[t * C_DIM + b];
        ls[t] = a;
    }
}

// s[i] = sum_c D[i,c] * ls[c]
__global__ void k_s(const float* __restrict__ D, const float* __restrict__ ls,
                    float* __restrict__ s) {
    int i = blockIdx.x * blockDim.x + threadIdx.x;
    float a = 0.f;
    for (int c = 0; c < C_DIM; ++c) a += D[i * C_DIM + c] * ls[c];
    s[i] = a;
}

// P (fp32, k-major) -> Ppack (bf16)
__global__ __launch_bounds__(256) void k_cvtP(const float* __restrict__ P,
                                              __hip_bfloat16* __restrict__ Pp) {
    int idx = (blockIdx.x * 256 + threadIdx.x) * 8;
    float4 a = *(const float4*)(P + idx);
    float4 b = *(const float4*)(P + idx + 4);
    __hip_bfloat16 h[8];
    h[0] = __float2bfloat16(a.x); h[1] = __float2bfloat16(a.y);
    h[2] = __float2bfloat16(a.z); h[3] = __float2bfloat16(a.w);
    h[4] = __float2bfloat16(b.x); h[5] = __float2bfloat16(b.y);
    h[6] = __float2bfloat16(b.z); h[7] = __float2bfloat16(b.w);
    *(bf16x8*)&Pp[idx] = *(bf16x8*)h;
}

// Wt[z][h][k] = W_z[k][h] in bf16 (64x64 tile transpose via LDS)
__global__ __launch_bounds__(256) void k_cvtW(const float* __restrict__ Ws,
                                              const float* __restrict__ Wo,
                                              __hip_bfloat16* __restrict__ Wt) {
    const int k0 = (blockIdx.x & 3) * 64;
    const int h0 = ((blockIdx.x >> 2) & 3) * 64;
    const int z  = blockIdx.x >> 4;
    const float* W = z ? Wo : Ws;
    __shared__ float T[64][65];
    const int t = threadIdx.x;
    #pragma unroll
    for (int q = 0; q < 4; ++q) {
        int r = (t >> 4) + q * 16;
        int c = (t & 15) * 4;
        float4 f = *(const float4*)&W[(size_t)(k0 + r) * H_DIM + h0 + c];
        T[r][c] = f.x; T[r][c+1] = f.y; T[r][c+2] = f.z; T[r][c+3] = f.w;
    }
    __syncthreads();
    #pragma unroll
    for (int q = 0; q < 2; ++q) {
        int idx = t + q * 256;
        int h   = idx >> 3;
        int kc  = idx & 7;
        __hip_bfloat16 u[8];
        #pragma unroll
        for (int j = 0; j < 8; ++j) u[j] = __float2bfloat16(T[kc * 8 + j][h]);
        *(bf16x8*)&Wt[((size_t)z * H_DIM + h0 + h) * H_DIM + k0 + kc * 8] = *(bf16x8*)u;
    }
}

// MFMA sub/obj: v = relu(P@W + b); fused pack write + bias-dot partials.
// Tile 128(rows) x 64(h), 4 waves (2x2), wave = 64x32, BK=32, 2-phase dbuf.
__global__ __launch_bounds__(256) void k_subobj(
    const ushort_t* __restrict__ Pp, const ushort_t* __restrict__ Wt,
    const float* __restrict__ bsub, const float* __restrict__ bobj,
    const float* __restrict__ wsc,
    __hip_bfloat16* __restrict__ Apack, __hip_bfloat16* __restrict__ Bpack,
    float* __restrict__ part) {
    const int hblk = blockIdx.x;             // 0..3
    const int i0   = blockIdx.y * 128;
    const int z    = blockIdx.z;
    const int j0   = hblk * 64;
    const float* bias = z ? bobj : bsub;
    const ushort_t* Wz = Wt + (size_t)z * H_DIM * H_DIM;

    __shared__ ushort_t As[2][128 * 32];
    __shared__ ushort_t Bs[2][64 * 32];

    const int t = threadIdx.x;
    const int w = t >> 6, l = t & 63;
    const int wr = w >> 1, wc = w & 1;
    const int lr = l & 15, g = l >> 4;

    f32x4 acc[4][2];
    #pragma unroll
    for (int m = 0; m < 4; ++m)
        #pragma unroll
        for (int n = 0; n < 2; ++n) acc[m][n] = f32x4{0.f, 0.f, 0.f, 0.f};

#define SO_STAGE(buf, ks) do {                                                  \
    int k0_ = (ks) * 32;                                                        \
    _Pragma("unroll")                                                           \
    for (int r_ = 0; r_ < 2; ++r_) {                                            \
        int idx_ = t + r_ * 256, row_ = idx_ >> 2, sc_ = (idx_&3)^(row_&3);     \
        __builtin_amdgcn_global_load_lds(                                       \
            (const __attribute__((address_space(1))) void*)(Pp + (size_t)(i0+row_)*H_DIM + k0_ + sc_*8), \
            (__attribute__((address_space(3))) void*)&As[buf][idx_*8], 16,0,0); \
    }                                                                           \
    { int row_ = t >> 2, sc_ = (t&3)^(row_&3);                                  \
      __builtin_amdgcn_global_load_lds(                                         \
            (const __attribute__((address_space(1))) void*)(Wz + (size_t)(j0+row_)*H_DIM + k0_ + sc_*8), \
            (__attribute__((address_space(3))) void*)&Bs[buf][t*8], 16,0,0); }  \
} while (0)

    SO_STAGE(0, 0);
    __syncthreads();
    for (int ks = 0; ks < 8; ++ks) {
        const int cur = ks & 1;
        if (ks < 7) SO_STAGE(cur ^ 1, ks + 1);
        bf16x8 a[4], b[2];
        #pragma unroll
        for (int m = 0; m < 4; ++m) {
            int Rl = wr * 64 + m * 16 + lr;
            int ch = (Rl << 2) | (g ^ (Rl & 3));
            a[m] = *(const bf16x8*)&As[cur][ch * 8];
        }
        #pragma unroll
        for (int n = 0; n < 2; ++n) {
            int Rl = wc * 32 + n * 16 + lr;
            int ch = (Rl << 2) | (g ^ (Rl & 3));
            b[n] = *(const bf16x8*)&Bs[cur][ch * 8];
        }
        #pragma unroll
        for (int m = 0; m < 4; ++m)
            #pragma unroll
            for (int n = 0; n < 2; ++n)
                acc[m][n] = __builtin_amdgcn_mfma_f32_16x16x32_bf16(
                    a[m], b[n], acc[m][n], 0, 0, 0);
        __syncthreads();
    }
#undef SO_STAGE

    // epilogue: relu+bias, pack write, per-row dot partials
    int hn[2]; float bb[2], wse[2], wmu[2];
    #pragma unroll
    for (int n = 0; n < 2; ++n) {
        hn[n]  = j0 + wc * 32 + n * 16 + lr;
        bb[n]  = bias[hn[n]];
        wse[n] = wsc[(z ? 512 : 256) + hn[n]];
        wmu[n] = wsc[hn[n]];
    }
    float* partq = part + (size_t)(z * 8 + hblk * 2 + wc) * N_DIM;
    #pragma unroll
    for (int m = 0; m < 4; ++m) {
        float p[4] = {0.f, 0.f, 0.f, 0.f};
        #pragma unroll
        for (int n = 0; n < 2; ++n)
            #pragma unroll
            for (int r = 0; r < 4; ++r) {
                float v = acc[m][n][r] + bb[n];
                v = v > 0.f ? v : 0.f;
                int i = i0 + wr * 64 + m * 16 + g * 4 + r;
                if (z) Apack[(size_t)i * KP + hn[n]] = __float2bfloat16(v * wmu[n]);
                else   Bpack[(size_t)i * KP + hn[n]] = __float2bfloat16(v);
                p[r] += v * wse[n];
            }
        #pragma unroll
        for (int r = 0; r < 4; ++r) {
            p[r] += __shfl_xor(p[r], 1);
            p[r] += __shfl_xor(p[r], 2);
            p[r] += __shfl_xor(p[r], 4);
            p[r] += __shfl_xor(p[r], 8);
        }
        if (lr == 0)
            #pragma unroll
            for (int r = 0; r < 4; ++r)
                partq[i0 + wr * 64 + m * 16 + g * 4 + r] = p[r];
    }
}

// Tail pack: Apack[i,256+t] = w_ps*D[i,t]; Bpack[i,256+t] = (D@co)[i,t]
__global__ __launch_bounds__(192) void k_pack_tail(
    const float* __restrict__ D, const float* __restrict__ co,
    const float* __restrict__ wsc,
    __hip_bfloat16* __restrict__ Apack, __hip_bfloat16* __restrict__ Bpack) {
    __shared__ float Drow[C_DIM];
    const int i = blockIdx.x;
    const int t = threadIdx.x;
    if (t < C_DIM) Drow[t] = D[(size_t)i * C_DIM + t];
    __syncthreads();
    if (t < KP - H_DIM) {
        float av = 0.f, bv = 0.f;
        if (t < C_DIM) {
            av = wsc[768] * Drow[t];
            float m = 0.f;
            for (int a = 0; a < C_DIM; ++a)
                m += Drow[a] * co[a * C_DIM + t];
            bv = m;
        }
        Apack[(size_t)i * KP + H_DIM + t] = __float2bfloat16(av);
        Bpack[(size_t)i * KP + H_DIM + t] = __float2bfloat16(bv);
    }
}

// rowbias[i] = sum part[8..16) + w_os*s ; colbias[i] = sum part[0..8) + w_ss*s + b
__global__ void k_finish(const float* __restrict__ part, const float* __restrict__ s,
                         const float* __restrict__ wsc, const float* __restrict__ bsc,
                         float* __restrict__ rowbias, float* __restrict__ colbias) {
    int i = blockIdx.x * 256 + threadIdx.x;
    float cc = 0.f, rc = 0.f;
    #pragma unroll
    for (int q = 0; q < 8; ++q)  cc += part[(size_t)q * N_DIM + i];
    #pragma unroll
    for (int q = 8; q < 16; ++q) rc += part[(size_t)q * N_DIM + i];
    rowbias[i] = rc + wsc[770] * s[i];
    colbias[i] = cc + wsc[769] * s[i] + bsc[0];
}

// Main: out[i,j] = sigmoid(A[i,:].B[j,:] + rowbias[i] + colbias[j])
// 128x128 tile, 4 waves, BK=32, 2-phase dbuf, LDS-bounce coalesced epilogue.
__global__ __launch_bounds__(256) void k_main(
    const ushort_t* __restrict__ Apack, const ushort_t* __restrict__ Bpack,
    const float* __restrict__ rowbias, const float* __restrict__ colbias,
    float* __restrict__ out) {
    __shared__ ushort_t pool[2][2][128 * 32];   // [buf][A|B], 32 KiB

    const int t = threadIdx.x;
    const int w = t >> 6, l = t & 63;
    const int wr = w >> 1, wc = w & 1;
    const int lr = l & 15, g = l >> 4;
    const int bid = blockIdx.x;
    const int swz = (bid & 7) * 128 + (bid >> 3);   // XCD-aware, 1024 % 8 == 0
    const int i0 = (swz >> 5) * 128;
    const int j0 = (swz & 31) * 128;

    f32x4 acc[4][4];
    #pragma unroll
    for (int m = 0; m < 4; ++m)
        #pragma unroll
        for (int n = 0; n < 4; ++n) acc[m][n] = f32x4{0.f, 0.f, 0.f, 0.f};

#define K_STAGE(buf, ks) do {                                                   \
    int k0_ = (ks) * 32;                                                        \
    _Pragma("unroll")                                                           \
    for (int r_ = 0; r_ < 2; ++r_) {                                            \
        int idx_ = t + r_ * 256, row_ = idx_ >> 2, sc_ = (idx_&3)^(row_&3);     \
        __builtin_amdgcn_global_load_lds(                                       \
            (const __attribute__((address_space(1))) void*)(Apack + (size_t)(i0+row_)*KP + k0_ + sc_*8), \
            (__attribute__((address_space(3))) void*)&pool[buf][0][idx_*8], 16,0,0); \
        __builtin_amdgcn_global_load_lds(                                       \
            (const __attribute__((address_space(1))) void*)(Bpack + (size_t)(j0+row_)*KP + k0_ + sc_*8), \
            (__attribute__((address_space(3))) void*)&pool[buf][1][idx_*8], 16,0,0); \
    }                                                                           \
} while (0)

    K_STAGE(0, 0);
    __syncthreads();
    for (int ks = 0; ks < KP / 32; ++ks) {
        const int cur = ks & 1;
        if (ks < KP / 32 - 1) K_STAGE(cur ^ 1, ks + 1);
        bf16x8 a[4], b[4];
        #pragma unroll
        for (int m = 0; m < 4; ++m) {
            int Rl = wr * 64 + m * 16 + lr;
            int ch = (Rl << 2) | (g ^ (Rl & 3));
            a[m] = *(const bf16x8*)&pool[cur][0][ch * 8];
        }
        #pragma unroll
        for (int n = 0; n < 4; ++n) {
            int Rl = wc * 64 + n * 16 + lr;
            int ch = (Rl << 2) | (g ^ (Rl & 3));
            b[n] = *(const bf16x8*)&pool[cur][1][ch * 8];
        }
        #pragma unroll
        for (int m = 0; m < 4; ++m)
            #pragma unroll
            for (int n = 0; n < 4; ++n)
                acc[m][n] = __builtin_amdgcn_mfma_f32_16x16x32_bf16(
                    a[m], b[n], acc[m][n], 0, 0, 0);
        __syncthreads();
    }
#undef K_STAGE

    // Epilogue: sigmoid -> LDS bounce -> coalesced float4 stores.
    float cbv[4];
    #pragma unroll
    for (int n = 0; n < 4; ++n) cbv[n] = colbias[j0 + wc * 64 + n * 16 + lr];
    float* OutS = (float*)pool;   // [32][132] per m-chunk, 16.9 KiB <= 32 KiB
    #pragma unroll
    for (int m = 0; m < 4; ++m) {
        float4 rbv = *(const float4*)&rowbias[i0 + wr * 64 + m * 16 + g * 4];
        #pragma unroll
        for (int n = 0; n < 4; ++n) {
            #pragma unroll
            for (int r = 0; r < 4; ++r) {
                float v = acc[m][n][r] + ((const float*)&rbv)[r] + cbv[n];
                OutS[(wr * 16 + g * 4 + r) * 132 + wc * 64 + n * 16 + lr] =
                    1.0f / (1.0f + __expf(-v));
            }
        }
        __syncthreads();
        {
            int rl = t >> 3, c8 = t & 7;
            int gr = i0 + m * 16 + (rl >> 4) * 64 + (rl & 15);
            float* op = out + (size_t)gr * N_DIM + j0;
            const float* rp = OutS + rl * 132;
            #pragma unroll
            for (int k = 0; k < 4; ++k) {
                float4 v4 = *(const float4*)(rp + (c8 + 8 * k) * 4);
                *(float4*)(op + (c8 + 8 * k) * 4) = v4;
            }
        }
        __syncthreads();
    }
}

extern "C" void kernel_launch(void* const* d_in, const int* in_sizes, int n_in,
                              void* d_out, int out_size, void* d_ws, size_t ws_size,
                              hipStream_t stream) {
    const float* prepro = (const float*)d_in[0];
    const float* D      = (const float*)d_in[1];
    const float* co     = (const float*)d_in[2];
    const float* Wsub   = (const float*)d_in[3];
    const float* bsub   = (const float*)d_in[4];
    const float* Wobj   = (const float*)d_in[5];
    const float* bobj   = (const float*)d_in[6];
    const float* wsc    = (const float*)d_in[7];
    const float* bsc    = (const float*)d_in[8];
    float* out = (float*)d_out;

    char* ws = (char*)d_ws;
    float* ls      = (float*)(ws + WSB_LS);
    float* s       = (float*)(ws + WSB_S);
    __hip_bfloat16* Ppack = (__hip_bfloat16*)(ws + WSB_PPACK);
    __hip_bfloat16* Wt    = (__hip_bfloat16*)(ws + WSB_WT);
    float* part    = (float*)(ws + WSB_PART);
    float* rowbias = (float*)(ws + WSB_ROWB);
    float* colbias = (float*)(ws + WSB_COLB);
    __hip_bfloat16* Apack = (__hip_bfloat16*)(ws + WSB_APACK);
    __hip_bfloat16* Bpack = (__hip_bfloat16*)(ws + WSB_BPACK);

    k_label<<<1, 256, 0, stream>>>(co, ls);
    k_s<<<N_DIM / 256, 256, 0, stream>>>(D, ls, s);
    k_cvtP<<<N_DIM * H_DIM / (256 * 8), 256, 0, stream>>>(prepro, Ppack);
    k_cvtW<<<32, 256, 0, stream>>>(Wsub, Wobj, Wt);
    k_subobj<<<dim3(4, N_DIM / 128, 2), 256, 0, stream>>>(
        (const ushort_t*)Ppack, (const ushort_t*)Wt, bsub, bobj, wsc,
        Apack, Bpack, part);
    k_pack_tail<<<N_DIM, 192, 0, stream>>>(D, co, wsc, Apack, Bpack);
    k_finish<<<N_DIM / 256, 256, 0, stream>>>(part, s, wsc, bsc, rowbias, colbias);
    k_main<<<1024, 256, 0, stream>>>(
        (const ushort_t*)Apack, (const ushort_t*)Bpack, rowbias, colbias, out);
}

// Round 4
// 89.776 us; speedup vs baseline: 2.7953x; 1.1276x over previous
//
#include <hip/hip_runtime.h>
#include <hip/hip_bf16.h>
#include <math.h>

#define N_DIM 4096
#define H_DIM 256
#define C_DIM 151
#define KP    448   // 256 + 192 (151 real + 41 zero); 7 K-steps of 64
#define TAIL  192

typedef unsigned short ushort_t;
typedef __attribute__((ext_vector_type(8))) short bf16x8;
typedef __attribute__((ext_vector_type(4))) float f32x4;

// ---------------- workspace layout (BYTE offsets) ----------------
#define WSB_S      0          // f32[4096]
#define WSB_PPACK  16384      // bf16[4096*256]
#define WSB_WT     2113536    // bf16[2][256*256] (W^T, k-contiguous)
#define WSB_PART   2375680    // f32[16][4096]
#define WSB_APACK  2637824    // bf16[4096*448]  (obj*w_mul | w_ps*D | 0)
#define WSB_BPACK  6307840    // bf16[4096*448]  (sub       | D@co   | 0)

#define GLL(src, dst) __builtin_amdgcn_global_load_lds( \
    (const __attribute__((address_space(1))) void*)(src), \
    (__attribute__((address_space(3))) void*)(dst), 16, 0, 0)

// Fused converts: blocks [0,512): P fp32->bf16 ; blocks [512,544): W transpose->bf16
__global__ __launch_bounds__(256) void k_cvt(
    const float* __restrict__ P, const float* __restrict__ Ws,
    const float* __restrict__ Wo, __hip_bfloat16* __restrict__ Pp,
    __hip_bfloat16* __restrict__ Wt) {
    __shared__ float T[64][65];
    const int t = threadIdx.x;
    if (blockIdx.x < 512) {
        int idx = (blockIdx.x * 256 + t) * 8;
        float4 a = *(const float4*)(P + idx);
        float4 b = *(const float4*)(P + idx + 4);
        __hip_bfloat16 h[8];
        h[0] = __float2bfloat16(a.x); h[1] = __float2bfloat16(a.y);
        h[2] = __float2bfloat16(a.z); h[3] = __float2bfloat16(a.w);
        h[4] = __float2bfloat16(b.x); h[5] = __float2bfloat16(b.y);
        h[6] = __float2bfloat16(b.z); h[7] = __float2bfloat16(b.w);
        *(bf16x8*)&Pp[idx] = *(bf16x8*)h;
    } else {
        const int b  = blockIdx.x - 512;
        const int k0 = (b & 3) * 64;
        const int h0 = ((b >> 2) & 3) * 64;
        const int z  = b >> 4;
        const float* W = z ? Wo : Ws;
        #pragma unroll
        for (int q = 0; q < 4; ++q) {
            int r = (t >> 4) + q * 16;
            int c = (t & 15) * 4;
            float4 f = *(const float4*)&W[(size_t)(k0 + r) * H_DIM + h0 + c];
            T[r][c] = f.x; T[r][c+1] = f.y; T[r][c+2] = f.z; T[r][c+3] = f.w;
        }
        __syncthreads();
        #pragma unroll
        for (int q = 0; q < 2; ++q) {
            int idx = t + q * 256;
            int h   = idx >> 3;
            int kc  = idx & 7;
            __hip_bfloat16 u[8];
            #pragma unroll
            for (int j = 0; j < 8; ++j) u[j] = __float2bfloat16(T[kc * 8 + j][h]);
            *(bf16x8*)&Wt[((size_t)z * H_DIM + h0 + h) * H_DIM + k0 + kc * 8] = *(bf16x8*)u;
        }
    }
}

// k_tail: co staged once in LDS. Computes ls, s, w_ps*D, D@co, zero-pad.
// grid 256 blocks x 16 rows.
__global__ __launch_bounds__(256) void k_tail(
    const float* __restrict__ D, const float* __restrict__ co,
    const float* __restrict__ wsc,
    __hip_bfloat16* __restrict__ Apack, __hip_bfloat16* __restrict__ Bpack,
    float* __restrict__ s_out) {
    __shared__ float coS[C_DIM * C_DIM];   // 91.2 KB
    __shared__ float lsS[C_DIM];
    __shared__ float Dl[16][C_DIM];
    const int t  = threadIdx.x;
    const int i0 = blockIdx.x * 16;
    for (int idx = t; idx < C_DIM * C_DIM; idx += 256) coS[idx] = co[idx];
    for (int idx = t; idx < 16 * C_DIM; idx += 256)
        Dl[idx / C_DIM][idx % C_DIM] = D[(size_t)i0 * C_DIM + idx];
    __syncthreads();
    if (t < C_DIM) {
        float a = 0.f;
        for (int b = 0; b < C_DIM; ++b) a += coS[t * C_DIM + b];
        lsS[t] = a;
    }
    __syncthreads();
    if (t < 16) {
        float a = 0.f;
        for (int c = 0; c < C_DIM; ++c) a += Dl[t][c] * lsS[c];
        s_out[i0 + t] = a;
    }
    const float wps = wsc[768];
    for (int o = t; o < 16 * TAIL; o += 256) {
        int r = o / TAIL, c = o % TAIL;
        float av = 0.f, bv = 0.f;
        if (c < C_DIM) {
            av = wps * Dl[r][c];
            float m = 0.f;
            for (int a = 0; a < C_DIM; ++a) m += Dl[r][a] * coS[a * C_DIM + c];
            bv = m;
        }
        Apack[(size_t)(i0 + r) * KP + H_DIM + c] = __float2bfloat16(av);
        Bpack[(size_t)(i0 + r) * KP + H_DIM + c] = __float2bfloat16(bv);
    }
}

// MFMA sub/obj: full-K single stage (no K-loop barriers). Tile 128x64, 4 waves.
__global__ __launch_bounds__(256) void k_subobj(
    const ushort_t* __restrict__ Pp, const ushort_t* __restrict__ Wt,
    const float* __restrict__ bsub, const float* __restrict__ bobj,
    const float* __restrict__ wsc,
    __hip_bfloat16* __restrict__ Apack, __hip_bfloat16* __restrict__ Bpack,
    float* __restrict__ part) {
    const int hblk = blockIdx.x;
    const int i0   = blockIdx.y * 128;
    const int z    = blockIdx.z;
    const int j0   = hblk * 64;
    const float* bias = z ? bobj : bsub;
    const ushort_t* Wz = Wt + (size_t)z * H_DIM * H_DIM;

    __shared__ ushort_t As[128 * 256];  // 64 KB
    __shared__ ushort_t Bs[64 * 256];   // 32 KB

    const int t = threadIdx.x;
    const int w = t >> 6, l = t & 63;
    const int wr = w >> 1, wc = w & 1;
    const int lr = l & 15, g = l >> 4;

    // stage A (128 rows x 32 chunks), B (64 rows x 32 chunks), XOR-swizzled source
    #pragma unroll
    for (int r_ = 0; r_ < 16; ++r_) {
        int idx = t + r_ * 256, row = idx >> 5, cl = idx & 31;
        int cs = cl ^ (row & 7);
        GLL(Pp + (size_t)(i0 + row) * H_DIM + cs * 8, &As[idx * 8]);
    }
    #pragma unroll
    for (int r_ = 0; r_ < 8; ++r_) {
        int idx = t + r_ * 256, row = idx >> 5, cl = idx & 31;
        int cs = cl ^ (row & 7);
        GLL(Wz + (size_t)(j0 + row) * H_DIM + cs * 8, &Bs[idx * 8]);
    }
    __syncthreads();

    f32x4 acc[4][2];
    #pragma unroll
    for (int m = 0; m < 4; ++m)
        #pragma unroll
        for (int n = 0; n < 2; ++n) acc[m][n] = f32x4{0.f, 0.f, 0.f, 0.f};

    #pragma unroll
    for (int ks2 = 0; ks2 < 8; ++ks2) {
        bf16x8 a[4], b[2];
        int c = ks2 * 4 + g;
        #pragma unroll
        for (int m = 0; m < 4; ++m) {
            int Rl = wr * 64 + m * 16 + lr;
            int cl = c ^ (Rl & 7);
            a[m] = *(const bf16x8*)&As[(Rl * 32 + cl) * 8];
        }
        #pragma unroll
        for (int n = 0; n < 2; ++n) {
            int Rl = wc * 32 + n * 16 + lr;
            int cl = c ^ (Rl & 7);
            b[n] = *(const bf16x8*)&Bs[(Rl * 32 + cl) * 8];
        }
        #pragma unroll
        for (int m = 0; m < 4; ++m)
            #pragma unroll
            for (int n = 0; n < 2; ++n)
                acc[m][n] = __builtin_amdgcn_mfma_f32_16x16x32_bf16(
                    a[m], b[n], acc[m][n], 0, 0, 0);
    }

    // epilogue: relu+bias, pack write, per-row bias-dot partials
    int hn[2]; float bb[2], wse[2], wmu[2];
    #pragma unroll
    for (int n = 0; n < 2; ++n) {
        hn[n]  = j0 + wc * 32 + n * 16 + lr;
        bb[n]  = bias[hn[n]];
        wse[n] = wsc[(z ? 512 : 256) + hn[n]];
        wmu[n] = wsc[hn[n]];
    }
    float* partq = part + (size_t)(z * 8 + hblk * 2 + wc) * N_DIM;
    #pragma unroll
    for (int m = 0; m < 4; ++m) {
        float p[4] = {0.f, 0.f, 0.f, 0.f};
        #pragma unroll
        for (int n = 0; n < 2; ++n)
            #pragma unroll
            for (int r = 0; r < 4; ++r) {
                float v = acc[m][n][r] + bb[n];
                v = v > 0.f ? v : 0.f;
                int i = i0 + wr * 64 + m * 16 + g * 4 + r;
                if (z) Apack[(size_t)i * KP + hn[n]] = __float2bfloat16(v * wmu[n]);
                else   Bpack[(size_t)i * KP + hn[n]] = __float2bfloat16(v);
                p[r] += v * wse[n];
            }
        #pragma unroll
        for (int r = 0; r < 4; ++r) {
            p[r] += __shfl_xor(p[r], 1);
            p[r] += __shfl_xor(p[r], 2);
            p[r] += __shfl_xor(p[r], 4);
            p[r] += __shfl_xor(p[r], 8);
        }
        if (lr == 0)
            #pragma unroll
            for (int r = 0; r < 4; ++r)
                partq[i0 + wr * 64 + m * 16 + g * 4 + r] = p[r];
    }
}

// Main: 256x256 tile, 8 waves (2M x 4N), BK=64, 2-phase dbuf.
// Fused bias computation in prologue; LDS-bounce coalesced epilogue.
__global__ __launch_bounds__(512, 2) void k_main(
    const ushort_t* __restrict__ Apack, const ushort_t* __restrict__ Bpack,
    const float* __restrict__ part, const float* __restrict__ s,
    const float* __restrict__ wsc, const float* __restrict__ bsc,
    float* __restrict__ out) {
    __shared__ ushort_t pool[2][2][256 * 64];   // 128 KB
    __shared__ float rbS[256], cbS[256];

    const int t = threadIdx.x;
    const int w = t >> 6, l = t & 63;
    const int wm = w >> 2, wn = w & 3;
    const int lr = l & 15, g = l >> 4;
    const int bid = blockIdx.x;
    const int swz = (bid & 7) * 32 + (bid >> 3);   // 256 % 8 == 0, bijective
    const int i0 = (swz >> 4) * 256;
    const int j0 = (swz & 15) * 256;

#define K_STAGE(buf, ks) do {                                                   \
    _Pragma("unroll")                                                           \
    for (int r_ = 0; r_ < 4; ++r_) {                                            \
        int idx_ = t + r_ * 512, row_ = idx_ >> 3, cl_ = idx_ & 7;              \
        int cs_ = cl_ ^ (row_ & 7);                                             \
        GLL(Apack + (size_t)(i0+row_)*KP + (ks)*64 + cs_*8, &pool[buf][0][idx_*8]); \
        GLL(Bpack + (size_t)(j0+row_)*KP + (ks)*64 + cs_*8, &pool[buf][1][idx_*8]); \
    }                                                                           \
} while (0)

    K_STAGE(0, 0);
    // fused bias computation (overlaps with stage-0 latency)
    if (t < 256) {
        int i = i0 + t; float r = 0.f;
        #pragma unroll
        for (int q = 8; q < 16; ++q) r += part[(size_t)q * N_DIM + i];
        rbS[t] = r + wsc[770] * s[i];
    } else {
        int j = j0 + (t - 256); float c = 0.f;
        #pragma unroll
        for (int q = 0; q < 8; ++q) c += part[(size_t)q * N_DIM + j];
        cbS[t - 256] = c + wsc[769] * s[j] + bsc[0];
    }
    __syncthreads();

    f32x4 acc[8][4];
    #pragma unroll
    for (int m = 0; m < 8; ++m)
        #pragma unroll
        for (int n = 0; n < 4; ++n) acc[m][n] = f32x4{0.f, 0.f, 0.f, 0.f};

    for (int ks = 0; ks < 7; ++ks) {
        const int cur = ks & 1;
        if (ks < 6) K_STAGE(cur ^ 1, ks + 1);
        #pragma unroll
        for (int ks2 = 0; ks2 < 2; ++ks2) {
            bf16x8 a[8], b[4];
            int c = ks2 * 4 + g;
            #pragma unroll
            for (int m = 0; m < 8; ++m) {
                int Rl = wm * 128 + m * 16 + lr;
                int cl = c ^ (Rl & 7);
                a[m] = *(const bf16x8*)&pool[cur][0][(Rl * 8 + cl) * 8];
            }
            #pragma unroll
            for (int n = 0; n < 4; ++n) {
                int Rl = wn * 64 + n * 16 + lr;
                int cl = c ^ (Rl & 7);
                b[n] = *(const bf16x8*)&pool[cur][1][(Rl * 8 + cl) * 8];
            }
            #pragma unroll
            for (int m = 0; m < 8; ++m)
                #pragma unroll
                for (int n = 0; n < 4; ++n)
                    acc[m][n] = __builtin_amdgcn_mfma_f32_16x16x32_bf16(
                        a[m], b[n], acc[m][n], 0, 0, 0);
        }
        __syncthreads();
    }
#undef K_STAGE

    // Epilogue: sigmoid -> LDS bounce (32 rows x 256 cols per m) -> float4 stores
    float cbv[4];
    #pragma unroll
    for (int n = 0; n < 4; ++n) cbv[n] = cbS[wn * 64 + n * 16 + lr];
    float* OutS = (float*)pool;   // [32][260] f32 = 33.3 KB
    #pragma unroll
    for (int m = 0; m < 8; ++m) {
        #pragma unroll
        for (int n = 0; n < 4; ++n) {
            #pragma unroll
            for (int r = 0; r < 4; ++r) {
                float rb = rbS[wm * 128 + m * 16 + g * 4 + r];
                float v  = acc[m][n][r] + rb + cbv[n];
                float e  = __expf(-v);
                OutS[(wm * 16 + g * 4 + r) * 260 + wn * 64 + n * 16 + lr] =
                    __builtin_amdgcn_rcpf(1.0f + e);
            }
        }
        __syncthreads();
        {
            int rl = t >> 4, c16 = t & 15;
            int gr = i0 + (rl >> 4) * 128 + m * 16 + (rl & 15);
            float* op = out + (size_t)gr * N_DIM + j0;
            const float* rp = OutS + rl * 260;
            #pragma unroll
            for (int k = 0; k < 4; ++k) {
                float4 v4 = *(const float4*)(rp + (c16 + 16 * k) * 4);
                *(float4*)(op + (c16 + 16 * k) * 4) = v4;
            }
        }
        __syncthreads();
    }
}

extern "C" void kernel_launch(void* const* d_in, const int* in_sizes, int n_in,
                              void* d_out, int out_size, void* d_ws, size_t ws_size,
                              hipStream_t stream) {
    const float* prepro = (const float*)d_in[0];
    const float* D      = (const float*)d_in[1];
    const float* co     = (const float*)d_in[2];
    const float* Wsub   = (const float*)d_in[3];
    const float* bsub   = (const float*)d_in[4];
    const float* Wobj   = (const float*)d_in[5];
    const float* bobj   = (const float*)d_in[6];
    const float* wsc    = (const float*)d_in[7];
    const float* bsc    = (const float*)d_in[8];
    float* out = (float*)d_out;

    char* ws = (char*)d_ws;
    float* s    = (float*)(ws + WSB_S);
    __hip_bfloat16* Ppack = (__hip_bfloat16*)(ws + WSB_PPACK);
    __hip_bfloat16* Wt    = (__hip_bfloat16*)(ws + WSB_WT);
    float* part = (float*)(ws + WSB_PART);
    __hip_bfloat16* Apack = (__hip_bfloat16*)(ws + WSB_APACK);
    __hip_bfloat16* Bpack = (__hip_bfloat16*)(ws + WSB_BPACK);

    k_cvt<<<544, 256, 0, stream>>>(prepro, Wsub, Wobj, Ppack, Wt);
    k_tail<<<256, 256, 0, stream>>>(D, co, wsc, Apack, Bpack, s);
    k_subobj<<<dim3(4, N_DIM / 128, 2), 256, 0, stream>>>(
        (const ushort_t*)Ppack, (const ushort_t*)Wt, bsub, bobj, wsc,
        Apack, Bpack, part);
    k_main<<<256, 512, 0, stream>>>(
        (const ushort_t*)Apack, (const ushort_t*)Bpack, part, s, wsc, bsc, out);
}

// Round 5
// 49.534 us; speedup vs baseline: 5.0662x; 1.8124x over previous
//
#include <hip/hip_runtime.h>
#include <hip/hip_bf16.h>
#include <math.h>

#define N_DIM 4096
#define H_DIM 256
#define C_DIM 151
#define KP    448   // 256 + 192 (151 real + 41 zero); 7 K-steps of 64
#define KT    160   // tail GEMM K: 151 padded to 160 (5 steps of 32)

typedef unsigned short ushort_t;
typedef __attribute__((ext_vector_type(8))) short bf16x8;
typedef __attribute__((ext_vector_type(4))) float f32x4;

// ---------------- workspace layout (BYTE offsets) ----------------
#define WSB_PPACK  0          // bf16[4096*256]
#define WSB_WT     2097152    // bf16[2][256*256]
#define WSB_DPACK  2359296    // bf16[4096*160]
#define WSB_COT    3670016    // bf16[192*160]   co^T, zero-padded
#define WSB_PART   3731456    // f32[16][4096]   bias-dot partials
#define WSB_SPART  3993600    // f32[6][4096]    s row-sum partials
#define WSB_APACK  4091904    // bf16[4096*448]  (obj*w_mul | w_ps*D | 0)
#define WSB_BPACK  7761920    // bf16[4096*448]  (sub       | D@co   | 0)

#define GLL(src, dst) __builtin_amdgcn_global_load_lds( \
    (const __attribute__((address_space(1))) void*)(src), \
    (__attribute__((address_space(3))) void*)(dst), 16, 0, 0)

// Fused converts:
//  [0,512)   P fp32->bf16
//  [512,544) W transpose -> Wt bf16
//  [544,608) D -> Dpack bf16 (pad 160) + Apack tail = bf16(w_ps*D) (pad 192)
//  [608,617) co -> coT bf16 (192x160, zero-padded)
__global__ __launch_bounds__(256) void k_cvt(
    const float* __restrict__ P, const float* __restrict__ Ws,
    const float* __restrict__ Wo, const float* __restrict__ D,
    const float* __restrict__ co, const float* __restrict__ wsc,
    __hip_bfloat16* __restrict__ Pp, __hip_bfloat16* __restrict__ Wt,
    __hip_bfloat16* __restrict__ Dpack, __hip_bfloat16* __restrict__ coT,
    __hip_bfloat16* __restrict__ Apack) {
    __shared__ float shbuf[64 * C_DIM];   // 38.7 KB; reused by all paths
    const int t = threadIdx.x;
    const int bid = blockIdx.x;
    if (bid < 512) {
        int idx = (bid * 256 + t) * 8;
        float4 a = *(const float4*)(P + idx);
        float4 b = *(const float4*)(P + idx + 4);
        __hip_bfloat16 h[8];
        h[0] = __float2bfloat16(a.x); h[1] = __float2bfloat16(a.y);
        h[2] = __float2bfloat16(a.z); h[3] = __float2bfloat16(a.w);
        h[4] = __float2bfloat16(b.x); h[5] = __float2bfloat16(b.y);
        h[6] = __float2bfloat16(b.z); h[7] = __float2bfloat16(b.w);
        *(bf16x8*)&Pp[idx] = *(bf16x8*)h;
    } else if (bid < 544) {
        const int b  = bid - 512;
        const int k0 = (b & 3) * 64;
        const int h0 = ((b >> 2) & 3) * 64;
        const int z  = b >> 4;
        const float* W = z ? Wo : Ws;
        #pragma unroll
        for (int q = 0; q < 4; ++q) {
            int r = (t >> 4) + q * 16;
            int c = (t & 15) * 4;
            float4 f = *(const float4*)&W[(size_t)(k0 + r) * H_DIM + h0 + c];
            shbuf[r * 65 + c] = f.x; shbuf[r * 65 + c + 1] = f.y;
            shbuf[r * 65 + c + 2] = f.z; shbuf[r * 65 + c + 3] = f.w;
        }
        __syncthreads();
        #pragma unroll
        for (int q = 0; q < 2; ++q) {
            int idx = t + q * 256;
            int h   = idx >> 3;
            int kc  = idx & 7;
            __hip_bfloat16 u[8];
            #pragma unroll
            for (int j = 0; j < 8; ++j)
                u[j] = __float2bfloat16(shbuf[(kc * 8 + j) * 65 + h]);
            *(bf16x8*)&Wt[((size_t)z * H_DIM + h0 + h) * H_DIM + k0 + kc * 8] = *(bf16x8*)u;
        }
    } else if (bid < 608) {
        const int b  = bid - 544;
        const int i0 = b * 64;
        for (int idx = t; idx < 64 * C_DIM; idx += 256)
            shbuf[idx] = D[(size_t)i0 * C_DIM + idx];
        __syncthreads();
        const float wps = wsc[768];
        for (int o = t; o < 64 * (KT / 8); o += 256) {
            int r = o / (KT / 8), ch = o % (KT / 8);
            __hip_bfloat16 u[8];
            #pragma unroll
            for (int j = 0; j < 8; ++j) {
                int k = ch * 8 + j;
                u[j] = __float2bfloat16(k < C_DIM ? shbuf[r * C_DIM + k] : 0.f);
            }
            *(bf16x8*)&Dpack[(size_t)(i0 + r) * KT + ch * 8] = *(bf16x8*)u;
        }
        for (int o = t; o < 64 * 24; o += 256) {
            int r = o / 24, ch = o % 24;
            __hip_bfloat16 u[8];
            #pragma unroll
            for (int j = 0; j < 8; ++j) {
                int c = ch * 8 + j;
                u[j] = __float2bfloat16(c < C_DIM ? wps * shbuf[r * C_DIM + c] : 0.f);
            }
            *(bf16x8*)&Apack[(size_t)(i0 + r) * KP + H_DIM + ch * 8] = *(bf16x8*)u;
        }
    } else {
        const int q  = bid - 608;
        const int a0 = (q % 3) * 64;   // K-dim tile
        const int c0 = (q / 3) * 64;   // col tile (becomes coT row)
        for (int o = t; o < 64 * 64; o += 256) {
            int r = o >> 6, c = o & 63;
            float v = 0.f;
            if (a0 + r < C_DIM && c0 + c < C_DIM)
                v = co[(size_t)(a0 + r) * C_DIM + c0 + c];
            shbuf[r * 65 + c] = v;
        }
        __syncthreads();
        const int nch = (a0 == 128) ? 4 : 8;   // clip to KT=160
        for (int o = t; o < 64 * 8; o += 256) {
            int cl = o >> 3, ch = o & 7;
            if (ch < nch) {
                __hip_bfloat16 u[8];
                #pragma unroll
                for (int j = 0; j < 8; ++j)
                    u[j] = __float2bfloat16(shbuf[(ch * 8 + j) * 65 + cl]);
                *(bf16x8*)&coT[(size_t)(c0 + cl) * KT + a0 + ch * 8] = *(bf16x8*)u;
            }
        }
    }
}

// Tail MFMA GEMM: M = D @ co (4096 x 192, K=160), fragments direct from global.
// Writes Bpack[:,256:448] = bf16(M) and spart (row-sum partials -> s).
// Tile 64x64, 4 waves (2x2), wave = 32x32. grid (3, 64).
__global__ __launch_bounds__(256) void k_tailmm(
    const ushort_t* __restrict__ Dpack, const ushort_t* __restrict__ coT,
    __hip_bfloat16* __restrict__ Bpack, float* __restrict__ spart) {
    const int t = threadIdx.x;
    const int w = t >> 6, l = t & 63;
    const int wr = w >> 1, wc = w & 1;
    const int lr = l & 15, g = l >> 4;
    const int j0 = blockIdx.x * 64;
    const int i0 = blockIdx.y * 64;

    bf16x8 a[2][5], b[2][5];
    #pragma unroll
    for (int m = 0; m < 2; ++m) {
        const ushort_t* ap = Dpack + (size_t)(i0 + wr * 32 + m * 16 + lr) * KT + g * 8;
        #pragma unroll
        for (int ks = 0; ks < 5; ++ks) a[m][ks] = *(const bf16x8*)(ap + ks * 32);
    }
    #pragma unroll
    for (int n = 0; n < 2; ++n) {
        const ushort_t* bp = coT + (size_t)(j0 + wc * 32 + n * 16 + lr) * KT + g * 8;
        #pragma unroll
        for (int ks = 0; ks < 5; ++ks) b[n][ks] = *(const bf16x8*)(bp + ks * 32);
    }

    f32x4 acc[2][2];
    #pragma unroll
    for (int m = 0; m < 2; ++m)
        #pragma unroll
        for (int n = 0; n < 2; ++n) acc[m][n] = f32x4{0.f, 0.f, 0.f, 0.f};
    #pragma unroll
    for (int ks = 0; ks < 5; ++ks)
        #pragma unroll
        for (int m = 0; m < 2; ++m)
            #pragma unroll
            for (int n = 0; n < 2; ++n)
                acc[m][n] = __builtin_amdgcn_mfma_f32_16x16x32_bf16(
                    a[m][ks], b[n][ks], acc[m][n], 0, 0, 0);

    float* sp = spart + (size_t)(blockIdx.x * 2 + wc) * N_DIM;
    #pragma unroll
    for (int m = 0; m < 2; ++m) {
        float p[4] = {0.f, 0.f, 0.f, 0.f};
        #pragma unroll
        for (int n = 0; n < 2; ++n) {
            int col = j0 + wc * 32 + n * 16 + lr;
            #pragma unroll
            for (int r = 0; r < 4; ++r) {
                int i = i0 + wr * 32 + m * 16 + g * 4 + r;
                float v = acc[m][n][r];
                Bpack[(size_t)i * KP + H_DIM + col] = __float2bfloat16(v);
                p[r] += v;
            }
        }
        #pragma unroll
        for (int r = 0; r < 4; ++r) {
            p[r] += __shfl_xor(p[r], 1);
            p[r] += __shfl_xor(p[r], 2);
            p[r] += __shfl_xor(p[r], 4);
            p[r] += __shfl_xor(p[r], 8);
        }
        if (lr == 0)
            #pragma unroll
            for (int r = 0; r < 4; ++r)
                sp[i0 + wr * 32 + m * 16 + g * 4 + r] = p[r];
    }
}

// MFMA sub/obj: full-K single stage. Tile 128x64, 4 waves.
__global__ __launch_bounds__(256) void k_subobj(
    const ushort_t* __restrict__ Pp, const ushort_t* __restrict__ Wt,
    const float* __restrict__ bsub, const float* __restrict__ bobj,
    const float* __restrict__ wsc,
    __hip_bfloat16* __restrict__ Apack, __hip_bfloat16* __restrict__ Bpack,
    float* __restrict__ part) {
    const int hblk = blockIdx.x;
    const int i0   = blockIdx.y * 128;
    const int z    = blockIdx.z;
    const int j0   = hblk * 64;
    const float* bias = z ? bobj : bsub;
    const ushort_t* Wz = Wt + (size_t)z * H_DIM * H_DIM;

    __shared__ ushort_t As[128 * 256];  // 64 KB
    __shared__ ushort_t Bs[64 * 256];   // 32 KB

    const int t = threadIdx.x;
    const int w = t >> 6, l = t & 63;
    const int wr = w >> 1, wc = w & 1;
    const int lr = l & 15, g = l >> 4;

    #pragma unroll
    for (int r_ = 0; r_ < 16; ++r_) {
        int idx = t + r_ * 256, row = idx >> 5, cl = idx & 31;
        int cs = cl ^ (row & 7);
        GLL(Pp + (size_t)(i0 + row) * H_DIM + cs * 8, &As[idx * 8]);
    }
    #pragma unroll
    for (int r_ = 0; r_ < 8; ++r_) {
        int idx = t + r_ * 256, row = idx >> 5, cl = idx & 31;
        int cs = cl ^ (row & 7);
        GLL(Wz + (size_t)(j0 + row) * H_DIM + cs * 8, &Bs[idx * 8]);
    }
    __syncthreads();

    f32x4 acc[4][2];
    #pragma unroll
    for (int m = 0; m < 4; ++m)
        #pragma unroll
        for (int n = 0; n < 2; ++n) acc[m][n] = f32x4{0.f, 0.f, 0.f, 0.f};

    #pragma unroll
    for (int ks2 = 0; ks2 < 8; ++ks2) {
        bf16x8 a[4], b[2];
        int c = ks2 * 4 + g;
        #pragma unroll
        for (int m = 0; m < 4; ++m) {
            int Rl = wr * 64 + m * 16 + lr;
            int cl = c ^ (Rl & 7);
            a[m] = *(const bf16x8*)&As[(Rl * 32 + cl) * 8];
        }
        #pragma unroll
        for (int n = 0; n < 2; ++n) {
            int Rl = wc * 32 + n * 16 + lr;
            int cl = c ^ (Rl & 7);
            b[n] = *(const bf16x8*)&Bs[(Rl * 32 + cl) * 8];
        }
        #pragma unroll
        for (int m = 0; m < 4; ++m)
            #pragma unroll
            for (int n = 0; n < 2; ++n)
                acc[m][n] = __builtin_amdgcn_mfma_f32_16x16x32_bf16(
                    a[m], b[n], acc[m][n], 0, 0, 0);
    }

    int hn[2]; float bb[2], wse[2], wmu[2];
    #pragma unroll
    for (int n = 0; n < 2; ++n) {
        hn[n]  = j0 + wc * 32 + n * 16 + lr;
        bb[n]  = bias[hn[n]];
        wse[n] = wsc[(z ? 512 : 256) + hn[n]];
        wmu[n] = wsc[hn[n]];
    }
    float* partq = part + (size_t)(z * 8 + hblk * 2 + wc) * N_DIM;
    #pragma unroll
    for (int m = 0; m < 4; ++m) {
        float p[4] = {0.f, 0.f, 0.f, 0.f};
        #pragma unroll
        for (int n = 0; n < 2; ++n)
            #pragma unroll
            for (int r = 0; r < 4; ++r) {
                float v = acc[m][n][r] + bb[n];
                v = v > 0.f ? v : 0.f;
                int i = i0 + wr * 64 + m * 16 + g * 4 + r;
                if (z) Apack[(size_t)i * KP + hn[n]] = __float2bfloat16(v * wmu[n]);
                else   Bpack[(size_t)i * KP + hn[n]] = __float2bfloat16(v);
                p[r] += v * wse[n];
            }
        #pragma unroll
        for (int r = 0; r < 4; ++r) {
            p[r] += __shfl_xor(p[r], 1);
            p[r] += __shfl_xor(p[r], 2);
            p[r] += __shfl_xor(p[r], 4);
            p[r] += __shfl_xor(p[r], 8);
        }
        if (lr == 0)
            #pragma unroll
            for (int r = 0; r < 4; ++r)
                partq[i0 + wr * 64 + m * 16 + g * 4 + r] = p[r];
    }
}

// Main: 256x256 tile, 8 waves (2M x 4N), BK=64, 2-phase dbuf.
__global__ __launch_bounds__(512, 2) void k_main(
    const ushort_t* __restrict__ Apack, const ushort_t* __restrict__ Bpack,
    const float* __restrict__ part, const float* __restrict__ spart,
    const float* __restrict__ wsc, const float* __restrict__ bsc,
    float* __restrict__ out) {
    __shared__ ushort_t pool[2][2][256 * 64];   // 128 KB
    __shared__ float rbS[256], cbS[256];

    const int t = threadIdx.x;
    const int w = t >> 6, l = t & 63;
    const int wm = w >> 2, wn = w & 3;
    const int lr = l & 15, g = l >> 4;
    const int bid = blockIdx.x;
    const int swz = (bid & 7) * 32 + (bid >> 3);
    const int i0 = (swz >> 4) * 256;
    const int j0 = (swz & 15) * 256;

#define K_STAGE(buf, ks) do {                                                   \
    _Pragma("unroll")                                                           \
    for (int r_ = 0; r_ < 4; ++r_) {                                            \
        int idx_ = t + r_ * 512, row_ = idx_ >> 3, cl_ = idx_ & 7;              \
        int cs_ = cl_ ^ (row_ & 7);                                             \
        GLL(Apack + (size_t)(i0+row_)*KP + (ks)*64 + cs_*8, &pool[buf][0][idx_*8]); \
        GLL(Bpack + (size_t)(j0+row_)*KP + (ks)*64 + cs_*8, &pool[buf][1][idx_*8]); \
    }                                                                           \
} while (0)

    K_STAGE(0, 0);
    if (t < 256) {
        int i = i0 + t; float r = 0.f, si = 0.f;
        #pragma unroll
        for (int q = 8; q < 16; ++q) r += part[(size_t)q * N_DIM + i];
        #pragma unroll
        for (int q = 0; q < 6; ++q) si += spart[(size_t)q * N_DIM + i];
        rbS[t] = r + wsc[770] * si;
    } else {
        int j = j0 + (t - 256); float c = 0.f, sj = 0.f;
        #pragma unroll
        for (int q = 0; q < 8; ++q) c += part[(size_t)q * N_DIM + j];
        #pragma unroll
        for (int q = 0; q < 6; ++q) sj += spart[(size_t)q * N_DIM + j];
        cbS[t - 256] = c + wsc[769] * sj + bsc[0];
    }
    __syncthreads();

    f32x4 acc[8][4];
    #pragma unroll
    for (int m = 0; m < 8; ++m)
        #pragma unroll
        for (int n = 0; n < 4; ++n) acc[m][n] = f32x4{0.f, 0.f, 0.f, 0.f};

    for (int ks = 0; ks < 7; ++ks) {
        const int cur = ks & 1;
        if (ks < 6) K_STAGE(cur ^ 1, ks + 1);
        #pragma unroll
        for (int ks2 = 0; ks2 < 2; ++ks2) {
            bf16x8 a[8], b[4];
            int c = ks2 * 4 + g;
            #pragma unroll
            for (int m = 0; m < 8; ++m) {
                int Rl = wm * 128 + m * 16 + lr;
                int cl = c ^ (Rl & 7);
                a[m] = *(const bf16x8*)&pool[cur][0][(Rl * 8 + cl) * 8];
            }
            #pragma unroll
            for (int n = 0; n < 4; ++n) {
                int Rl = wn * 64 + n * 16 + lr;
                int cl = c ^ (Rl & 7);
                b[n] = *(const bf16x8*)&pool[cur][1][(Rl * 8 + cl) * 8];
            }
            #pragma unroll
            for (int m = 0; m < 8; ++m)
                #pragma unroll
                for (int n = 0; n < 4; ++n)
                    acc[m][n] = __builtin_amdgcn_mfma_f32_16x16x32_bf16(
                        a[m], b[n], acc[m][n], 0, 0, 0);
        }
        __syncthreads();
    }
#undef K_STAGE

    float cbv[4];
    #pragma unroll
    for (int n = 0; n < 4; ++n) cbv[n] = cbS[wn * 64 + n * 16 + lr];
    float* OutS = (float*)pool;
    #pragma unroll
    for (int m = 0; m < 8; ++m) {
        #pragma unroll
        for (int n = 0; n < 4; ++n) {
            #pragma unroll
            for (int r = 0; r < 4; ++r) {
                float rb = rbS[wm * 128 + m * 16 + g * 4 + r];
                float v  = acc[m][n][r] + rb + cbv[n];
                float e  = __expf(-v);
                OutS[(wm * 16 + g * 4 + r) * 260 + wn * 64 + n * 16 + lr] =
                    __builtin_amdgcn_rcpf(1.0f + e);
            }
        }
        __syncthreads();
        {
            int rl = t >> 4, c16 = t & 15;
            int gr = i0 + (rl >> 4) * 128 + m * 16 + (rl & 15);
            float* op = out + (size_t)gr * N_DIM + j0;
            const float* rp = OutS + rl * 260;
            #pragma unroll
            for (int k = 0; k < 4; ++k) {
                float4 v4 = *(const float4*)(rp + (c16 + 16 * k) * 4);
                *(float4*)(op + (c16 + 16 * k) * 4) = v4;
            }
        }
        __syncthreads();
    }
}

extern "C" void kernel_launch(void* const* d_in, const int* in_sizes, int n_in,
                              void* d_out, int out_size, void* d_ws, size_t ws_size,
                              hipStream_t stream) {
    const float* prepro = (const float*)d_in[0];
    const float* D      = (const float*)d_in[1];
    const float* co     = (const float*)d_in[2];
    const float* Wsub   = (const float*)d_in[3];
    const float* bsub   = (const float*)d_in[4];
    const float* Wobj   = (const float*)d_in[5];
    const float* bobj   = (const float*)d_in[6];
    const float* wsc    = (const float*)d_in[7];
    const float* bsc    = (const float*)d_in[8];
    float* out = (float*)d_out;

    char* ws = (char*)d_ws;
    __hip_bfloat16* Ppack = (__hip_bfloat16*)(ws + WSB_PPACK);
    __hip_bfloat16* Wt    = (__hip_bfloat16*)(ws + WSB_WT);
    __hip_bfloat16* Dpack = (__hip_bfloat16*)(ws + WSB_DPACK);
    __hip_bfloat16* coT   = (__hip_bfloat16*)(ws + WSB_COT);
    float* part  = (float*)(ws + WSB_PART);
    float* spart = (float*)(ws + WSB_SPART);
    __hip_bfloat16* Apack = (__hip_bfloat16*)(ws + WSB_APACK);
    __hip_bfloat16* Bpack = (__hip_bfloat16*)(ws + WSB_BPACK);

    k_cvt<<<617, 256, 0, stream>>>(prepro, Wsub, Wobj, D, co, wsc,
                                   Ppack, Wt, Dpack, coT, Apack);
    k_tailmm<<<dim3(3, 64), 256, 0, stream>>>(
        (const ushort_t*)Dpack, (const ushort_t*)coT, Bpack, spart);
    k_subobj<<<dim3(4, N_DIM / 128, 2), 256, 0, stream>>>(
        (const ushort_t*)Ppack, (const ushort_t*)Wt, bsub, bobj, wsc,
        Apack, Bpack, part);
    k_main<<<256, 512, 0, stream>>>(
        (const ushort_t*)Apack, (const ushort_t*)Bpack, part, spart, wsc, bsc, out);
}